// Round 3
// baseline (290.278 us; speedup 1.0000x reference)
//
#include <hip/hip_runtime.h>
#include <hip/hip_bf16.h>

#define TT 2048

typedef __attribute__((ext_vector_type(4))) float f32x4;
typedef __attribute__((ext_vector_type(8))) __bf16 bf16x8;
typedef __attribute__((ext_vector_type(4))) short short4v;

enum { M_CONV = 0, M_QKV = 1, M_PROJ = 2, M_FFN1 = 3, M_FFN2 = 4 };

__device__ __forceinline__ void gload16(const void* g, void* l) {
    __builtin_amdgcn_global_load_lds(
        (__attribute__((address_space(1))) void*)g,
        (__attribute__((address_space(3))) void*)l, 16, 0, 0);
}

__device__ __forceinline__ short f2bf(float f) {
    unsigned u = __float_as_uint(f);
    u = (u + 0x7fffu + ((u >> 16) & 1u)) >> 16;
    return (short)u;
}

__device__ __forceinline__ bf16x8 mfma_bf16(bf16x8 a, bf16x8 b);  // unused decl guard

// ---------------------------------------------------------------------------
// One fused cast kernel: all weight transposes + padded x cast. 4,982,784 elems.
// ---------------------------------------------------------------------------
__global__ void cast_all(const float* __restrict__ conv_w, const float* __restrict__ qkv_w,
                         const float* __restrict__ proj_w, const float* __restrict__ ffn_w1,
                         const float* __restrict__ ffn_w2, const float* __restrict__ x,
                         short* __restrict__ cwT, short* __restrict__ qkvT,
                         short* __restrict__ projT, short* __restrict__ f1T,
                         short* __restrict__ f2T, short* __restrict__ xpad) {
    int idx = blockIdx.x * 256 + threadIdx.x;
    if (idx < 786432) {                       // conv_w OIH -> [o][tap*512+i]
        int tap = idx >> 18, i = (idx >> 9) & 511, o = idx & 511;
        cwT[(size_t)o * 1536 + tap * 512 + i] = f2bf(conv_w[((size_t)o * 512 + i) * 3 + tap]);
        return;
    }
    idx -= 786432;
    if (idx < 786432) {                       // qkv_w [512][1536] -> [n][k]
        int n = idx >> 9, k = idx & 511;
        qkvT[idx] = f2bf(qkv_w[(size_t)k * 1536 + n]);
        return;
    }
    idx -= 786432;
    if (idx < 262144) {                       // proj_w [512][512] -> [n][k]
        int n = idx >> 9, k = idx & 511;
        projT[idx] = f2bf(proj_w[(size_t)k * 512 + n]);
        return;
    }
    idx -= 262144;
    if (idx < 524288) {                       // ffn_w1 [512][1024] -> [n][k]
        int n = idx >> 9, k = idx & 511;
        f1T[idx] = f2bf(ffn_w1[(size_t)k * 1024 + n]);
        return;
    }
    idx -= 524288;
    if (idx < 524288) {                       // ffn_w2 [1024][512] -> [n][k]
        int n = idx >> 10, k = idx & 1023;
        f2T[idx] = f2bf(ffn_w2[(size_t)k * 512 + n]);
        return;
    }
    idx -= 524288;
    if (idx < 2099200) {                      // x -> xpad [2][2050][512] bf16
        int i = idx & 511, rp = idx >> 9;
        int bb = rp / 2050, rr = rp - bb * 2050;
        int t = rr - 2;
        float v = (t >= 0) ? x[((size_t)(bb << 11) + t) * 512 + i] : 0.f;
        xpad[((size_t)bb * 2050 + rr) * 512 + i] = f2bf(v);
    }
}

// ---------------------------------------------------------------------------
// Row LayerNorm over C=512: f32 in -> f32 out + optional bf16 out
// ---------------------------------------------------------------------------
__global__ __launch_bounds__(256) void ln2_kernel(const float* __restrict__ in,
                                                  const float* __restrict__ g,
                                                  const float* __restrict__ b,
                                                  float* __restrict__ outf,
                                                  short* __restrict__ outb) {
    int row = blockIdx.x;
    int tid = threadIdx.x;
    const float* p = in + (size_t)row * 512;
    float2 v = *(const float2*)(p + tid * 2);
    float s = v.x + v.y;
    float ss = v.x * v.x + v.y * v.y;
    #pragma unroll
    for (int off = 1; off < 64; off <<= 1) {
        s  += __shfl_xor(s, off);
        ss += __shfl_xor(ss, off);
    }
    __shared__ float sm[4], sm2[4];
    int w = tid >> 6;
    if ((tid & 63) == 0) { sm[w] = s; sm2[w] = ss; }
    __syncthreads();
    s  = sm[0] + sm[1] + sm[2] + sm[3];
    ss = sm2[0] + sm2[1] + sm2[2] + sm2[3];
    float mean = s * (1.f / 512);
    float var  = ss * (1.f / 512) - mean * mean;
    float rstd = rsqrtf(var + 1e-5f);
    float2 gg = *(const float2*)(g + tid * 2);
    float2 bb = *(const float2*)(b + tid * 2);
    float ox = (v.x - mean) * rstd * gg.x + bb.x;
    float oy = (v.y - mean) * rstd * gg.y + bb.y;
    *(float2*)(outf + (size_t)row * 512 + tid * 2) = make_float2(ox, oy);
    if (outb) {
        unsigned pk = ((unsigned)(unsigned short)f2bf(oy) << 16) |
                      (unsigned)(unsigned short)f2bf(ox);
        *(unsigned*)&outb[(size_t)row * 512 + tid * 2] = pk;
    }
}

// ---------------------------------------------------------------------------
// A-operand global address (handles conv's padded/3-tap layout)
// ---------------------------------------------------------------------------
template<int MODE>
__device__ __forceinline__ const short* a_ptr(const short* A, int m0, int r, int kk, int K) {
    if constexpr (MODE == M_CONV) {
        int row = m0 + r;
        int bb = row >> 11, t5 = row & 2047;
        int tap = kk >> 9, k2 = kk & 511;
        return A + ((size_t)(bb * 2050 + t5 + tap) * 512 + k2);
    } else {
        return A + ((size_t)(m0 + r) * K + kk);
    }
}

// ---------------------------------------------------------------------------
// bf16 MFMA GEMM, BK=64, double-buffered LDS, reg-prefetch (T14), single
// barrier per K-step. BM=128, BN=64, 4 waves (2x2), wave tile 64x32.
// LDS chunk-swizzled (chunk ^= row&7) via swizzled global source + swizzled
// read (rule #21: both-sides-or-neither).
// ---------------------------------------------------------------------------
template<int MODE>
__global__ __launch_bounds__(256) void gemm_mfma(
    const short* __restrict__ A, const short* __restrict__ Bw,
    const float* __restrict__ bias, const float* __restrict__ res,
    void* __restrict__ Cout, short* __restrict__ vTb, int K) {
    constexpr int BN = 64, NF = 2;
    constexpr int ACH = 4, BCH = 2;     // 16B chunks per thread
    __shared__ short As[2][128 * 64];
    __shared__ short Bs[2][64 * 64];
    const int tid = threadIdx.x;
    const int w = tid >> 6, l = tid & 63;
    const int wm = w >> 1, wn = w & 1;
    const int lr = l & 15, lc = l >> 4;
    const int m0 = blockIdx.y * 128, n0 = blockIdx.x * BN;

    f32x4 acc[4][NF];
    #pragma unroll
    for (int mf = 0; mf < 4; mf++)
        #pragma unroll
        for (int nf = 0; nf < NF; nf++) acc[mf][nf] = (f32x4){0.f, 0.f, 0.f, 0.f};

    // prologue: stage k-slab 0 (swizzled source chunk -> linear LDS)
    #pragma unroll
    for (int i = 0; i < ACH; i++) {
        int u = i * 256 + tid, r = u >> 3, c = (u & 7) ^ (r & 7);
        gload16(a_ptr<MODE>(A, m0, r, c * 8, K), (char*)As[0] + u * 16);
    }
    #pragma unroll
    for (int i = 0; i < BCH; i++) {
        int u = i * 256 + tid, r = u >> 3, c = (u & 7) ^ (r & 7);
        gload16(Bw + ((size_t)(n0 + r) * K + c * 8), (char*)Bs[0] + u * 16);
    }
    __syncthreads();

    const int NIT = K >> 6;
    for (int it = 0; it < NIT; it++) {
        const int cur = it & 1;
        float4 pa[ACH], pb[BCH];
        const bool pf = (it + 1) < NIT;
        if (pf) {
            int k0n = (it + 1) << 6;
            #pragma unroll
            for (int i = 0; i < ACH; i++) {
                int u = i * 256 + tid, r = u >> 3, c = (u & 7) ^ (r & 7);
                pa[i] = *(const float4*)a_ptr<MODE>(A, m0, r, k0n + c * 8, K);
            }
            #pragma unroll
            for (int i = 0; i < BCH; i++) {
                int u = i * 256 + tid, r = u >> 3, c = (u & 7) ^ (r & 7);
                pb[i] = *(const float4*)(Bw + ((size_t)(n0 + r) * K + k0n + c * 8));
            }
        }
        bf16x8 af[4][2];
        #pragma unroll
        for (int mf = 0; mf < 4; mf++)
            #pragma unroll
            for (int ks = 0; ks < 2; ks++) {
                int rr = wm * 64 + mf * 16 + lr;
                int cc = (ks * 4 + lc) ^ (rr & 7);
                af[mf][ks] = *(const bf16x8*)&As[cur][rr * 64 + cc * 8];
            }
        __builtin_amdgcn_s_setprio(1);
        #pragma unroll
        for (int nf = 0; nf < NF; nf++) {
            #pragma unroll
            for (int ks = 0; ks < 2; ks++) {
                int rr = wn * 32 + nf * 16 + lr;
                int cc = (ks * 4 + lc) ^ (rr & 7);
                bf16x8 bfr = *(const bf16x8*)&Bs[cur][rr * 64 + cc * 8];
                #pragma unroll
                for (int mf = 0; mf < 4; mf++)
                    acc[mf][nf] = __builtin_amdgcn_mfma_f32_16x16x32_bf16(
                        af[mf][ks], bfr, acc[mf][nf], 0, 0, 0);
            }
        }
        __builtin_amdgcn_s_setprio(0);
        if (pf) {
            #pragma unroll
            for (int i = 0; i < ACH; i++) {
                int u = i * 256 + tid;
                *(float4*)((char*)As[cur ^ 1] + u * 16) = pa[i];
            }
            #pragma unroll
            for (int i = 0; i < BCH; i++) {
                int u = i * 256 + tid;
                *(float4*)((char*)Bs[cur ^ 1] + u * 16) = pb[i];
            }
        }
        __syncthreads();
    }
    // epilogue
    #pragma unroll
    for (int mf = 0; mf < 4; mf++) {
        int row0 = m0 + wm * 64 + mf * 16 + lc * 4;
        #pragma unroll
        for (int nf = 0; nf < NF; nf++) {
            int col = n0 + wn * 32 + nf * 16 + lr;
            float bv = bias[col];
            if constexpr (MODE == M_CONV || MODE == M_PROJ || MODE == M_FFN2) {
                float* Cf = (float*)Cout;
                #pragma unroll
                for (int rg = 0; rg < 4; rg++) {
                    size_t off = (size_t)(row0 + rg) * 512 + col;
                    Cf[off] = acc[mf][nf][rg] + bv + res[off];
                }
            } else if constexpr (MODE == M_FFN1) {
                short* Cb = (short*)Cout;
                #pragma unroll
                for (int rg = 0; rg < 4; rg++)
                    Cb[(size_t)(row0 + rg) * 1024 + col] =
                        f2bf(fmaxf(acc[mf][nf][rg] + bv, 0.f));
            } else {  // M_QKV
                short* Cb = (short*)Cout;
                float v[4];
                #pragma unroll
                for (int rg = 0; rg < 4; rg++) {
                    v[rg] = acc[mf][nf][rg] + bv;
                    Cb[(size_t)(row0 + rg) * 1536 + col] = f2bf(v[rg]);
                }
                if (col >= 1024) {  // V transposed: vT[bh][d][t]
                    int vc = col - 1024, hh = vc >> 6, dd = vc & 63;
                    int bb = row0 >> 11, t5 = row0 & 2047;
                    short4v pk = {f2bf(v[0]), f2bf(v[1]), f2bf(v[2]), f2bf(v[3])};
                    *(short4v*)&vTb[((size_t)((bb << 3) + hh) * 64 + dd) * 2048 + t5] = pk;
                }
            }
        }
    }
}

// ---------------------------------------------------------------------------
// bf16 MFMA flash attention, 512 blocks (one per Q-tile), double-buffered
// K/V via reg-prefetch (T14), single barrier/iter, defer-max (T13), setprio.
// Block decode: bh = L&15 (XCD-clusters same-bh), qt = 31-(L>>4) (LPT order).
// ---------------------------------------------------------------------------
__global__ __launch_bounds__(256) void attn_mfma(const short* __restrict__ qkvb,
                                                 const short* __restrict__ vTb,
                                                 short* __restrict__ aout) {
    __shared__ short Qs[64 * 64];
    __shared__ short Ks[2][64 * 64];
    __shared__ short Vs[2][64 * 64];
    __shared__ short Ps[64 * 72];
    const int tid = threadIdx.x;
    const int w = tid >> 6, l = tid & 63;
    const int lr = l & 15, lc = l >> 4;
    const int L = blockIdx.x;
    const int bh = L & 15;
    const int qt = 31 - (L >> 4);
    const int b = bh >> 3, h = bh & 7;
    const int qr = w * 16, q0 = qt * 64;

    // prologue: Q + K/V tile 0
    #pragma unroll
    for (int i = 0; i < 2; i++) {
        int u = i * 256 + tid, r = u >> 3, c = (u & 7) ^ (r & 7);
        gload16(qkvb + ((size_t)(b * 2048 + q0 + r) * 1536 + h * 64 + c * 8),
                (char*)Qs + u * 16);
    }
    #pragma unroll
    for (int i = 0; i < 2; i++) {
        int u = i * 256 + tid, r = u >> 3, c = (u & 7) ^ (r & 7);
        gload16(qkvb + ((size_t)(b * 2048 + r) * 1536 + 512 + h * 64 + c * 8),
                (char*)Ks[0] + u * 16);
    }
    #pragma unroll
    for (int i = 0; i < 2; i++) {
        int u = i * 256 + tid, r = u >> 3, c = (u & 7) ^ (r & 7);
        gload16(vTb + ((size_t)(bh * 64 + r) * 2048 + c * 8), (char*)Vs[0] + u * 16);
    }
    __syncthreads();

    f32x4 o[4];
    float mst[4], lst[4];
    #pragma unroll
    for (int nf = 0; nf < 4; nf++) o[nf] = (f32x4){0.f, 0.f, 0.f, 0.f};
    #pragma unroll
    for (int rg = 0; rg < 4; rg++) { mst[rg] = -1e30f; lst[rg] = 0.f; }

    for (int kt = 0; kt <= qt; kt++) {
        const int cur = kt & 1;
        const bool pf = kt < qt;
        float4 pk[2], pv[2];
        if (pf) {
            #pragma unroll
            for (int i = 0; i < 2; i++) {
                int u = i * 256 + tid, r = u >> 3, c = (u & 7) ^ (r & 7);
                pk[i] = *(const float4*)(qkvb +
                    ((size_t)(b * 2048 + (kt + 1) * 64 + r) * 1536 + 512 + h * 64 + c * 8));
                pv[i] = *(const float4*)(vTb +
                    ((size_t)(bh * 64 + r) * 2048 + (kt + 1) * 64 + c * 8));
            }
        }
        // ---- S = Q @ K^T ----
        f32x4 s[4];
        #pragma unroll
        for (int nf = 0; nf < 4; nf++) s[nf] = (f32x4){0.f, 0.f, 0.f, 0.f};
        bf16x8 aq[2];
        #pragma unroll
        for (int ks = 0; ks < 2; ks++) {
            int rr = qr + lr;
            int cc = (lc + 4 * ks) ^ (rr & 7);
            aq[ks] = *(const bf16x8*)&Qs[rr * 64 + cc * 8];
        }
        __builtin_amdgcn_s_setprio(1);
        #pragma unroll
        for (int nf = 0; nf < 4; nf++) {
            #pragma unroll
            for (int ks = 0; ks < 2; ks++) {
                int rr = nf * 16 + lr;
                int cc = (lc + 4 * ks) ^ (rr & 7);
                bf16x8 bk = *(const bf16x8*)&Ks[cur][rr * 64 + cc * 8];
                s[nf] = __builtin_amdgcn_mfma_f32_16x16x32_bf16(aq[ks], bk, s[nf], 0, 0, 0);
            }
        }
        __builtin_amdgcn_s_setprio(0);
        // ---- online softmax with defer-max ----
        const bool diag = (kt == qt);
        #pragma unroll
        for (int nf = 0; nf < 4; nf++) {
            #pragma unroll
            for (int rg = 0; rg < 4; rg++) {
                float v = s[nf][rg] * 0.125f;
                if (diag) {
                    int cb = kt * 64 + nf * 16 + lr;
                    int row_g = q0 + qr + lc * 4 + rg;
                    if (cb > row_g) v = -1e30f;
                }
                s[nf][rg] = v;
            }
        }
        float rm[4];
        int ok = 1;
        #pragma unroll
        for (int rg = 0; rg < 4; rg++) {
            float m_ = fmaxf(fmaxf(s[0][rg], s[1][rg]), fmaxf(s[2][rg], s[3][rg]));
            m_ = fmaxf(m_, __shfl_xor(m_, 1));
            m_ = fmaxf(m_, __shfl_xor(m_, 2));
            m_ = fmaxf(m_, __shfl_xor(m_, 4));
            m_ = fmaxf(m_, __shfl_xor(m_, 8));
            rm[rg] = m_;
            ok &= (m_ <= mst[rg] + 8.f);
        }
        if (!__all(ok)) {
            #pragma unroll
            for (int rg = 0; rg < 4; rg++) {
                float mn = fmaxf(mst[rg], rm[rg]);
                float alpha = __expf(mst[rg] - mn);
                mst[rg] = mn;
                lst[rg] *= alpha;
                #pragma unroll
                for (int nf = 0; nf < 4; nf++) o[nf][rg] *= alpha;
            }
        }
        #pragma unroll
        for (int rg = 0; rg < 4; rg++) {
            float p0 = __expf(s[0][rg] - mst[rg]);
            float p1 = __expf(s[1][rg] - mst[rg]);
            float p2 = __expf(s[2][rg] - mst[rg]);
            float p3 = __expf(s[3][rg] - mst[rg]);
            int prow = (qr + lc * 4 + rg) * 72;
            Ps[prow      + lr] = f2bf(p0);
            Ps[prow + 16 + lr] = f2bf(p1);
            Ps[prow + 32 + lr] = f2bf(p2);
            Ps[prow + 48 + lr] = f2bf(p3);
            float rs = p0 + p1 + p2 + p3;
            rs += __shfl_xor(rs, 1);
            rs += __shfl_xor(rs, 2);
            rs += __shfl_xor(rs, 4);
            rs += __shfl_xor(rs, 8);
            lst[rg] += rs;
        }
        // ---- O += P @ V ----
        bf16x8 pa[2];
        #pragma unroll
        for (int ks = 0; ks < 2; ks++)
            pa[ks] = *(const bf16x8*)&Ps[(qr + lr) * 72 + ks * 32 + lc * 8];
        __builtin_amdgcn_s_setprio(1);
        #pragma unroll
        for (int nf = 0; nf < 4; nf++) {
            #pragma unroll
            for (int ks = 0; ks < 2; ks++) {
                int rr = nf * 16 + lr;
                int cc = (lc + 4 * ks) ^ (rr & 7);
                bf16x8 bv = *(const bf16x8*)&Vs[cur][rr * 64 + cc * 8];
                o[nf] = __builtin_amdgcn_mfma_f32_16x16x32_bf16(pa[ks], bv, o[nf], 0, 0, 0);
            }
        }
        __builtin_amdgcn_s_setprio(0);
        // ---- write prefetched tile into other buffer; one barrier ----
        if (pf) {
            #pragma unroll
            for (int i = 0; i < 2; i++) {
                int u = i * 256 + tid;
                *(float4*)((char*)Ks[cur ^ 1] + u * 16) = pk[i];
                *(float4*)((char*)Vs[cur ^ 1] + u * 16) = pv[i];
            }
        }
        __syncthreads();
    }
    #pragma unroll
    for (int nf = 0; nf < 4; nf++) {
        #pragma unroll
        for (int rg = 0; rg < 4; rg++) {
            float ov = o[nf][rg] / lst[rg];
            aout[(size_t)(b * 2048 + q0 + qr + lc * 4 + rg) * 512 + h * 64 + nf * 16 + lr] =
                f2bf(ov);
        }
    }
}

// ---------------------------------------------------------------------------
extern "C" void kernel_launch(void* const* d_in, const int* in_sizes, int n_in,
                              void* d_out, int out_size, void* d_ws, size_t ws_size,
                              hipStream_t stream) {
    const float* x      = (const float*)d_in[0];
    const float* conv_w = (const float*)d_in[1];
    const float* conv_b = (const float*)d_in[2];
    const float* g1     = (const float*)d_in[3];
    const float* b1     = (const float*)d_in[4];
    const float* qkv_w  = (const float*)d_in[5];
    const float* qkv_b  = (const float*)d_in[6];
    const float* proj_w = (const float*)d_in[7];
    const float* proj_b = (const float*)d_in[8];
    const float* g2     = (const float*)d_in[9];
    const float* b2     = (const float*)d_in[10];
    const float* ffn_w1 = (const float*)d_in[11];
    const float* ffn_b1 = (const float*)d_in[12];
    const float* ffn_w2 = (const float*)d_in[13];
    const float* ffn_b2 = (const float*)d_in[14];
    const float* g3     = (const float*)d_in[15];
    const float* b3     = (const float*)d_in[16];
    float* out = (float*)d_out;

    char* p = (char*)d_ws;
    short* cwT   = (short*)p;  p += 786432 * 2;
    short* qkvT  = (short*)p;  p += 786432 * 2;
    short* projT = (short*)p;  p += 262144 * 2;
    short* f1T   = (short*)p;  p += 524288 * 2;
    short* f2T   = (short*)p;  p += 524288 * 2;
    short* xpad  = (short*)p;  p += 2099200 * 2;
    float* yb    = (float*)p;  p += 2097152 * 4;
    float* x1f   = (float*)p;  p += 2097152 * 4;
    short* x1b   = (short*)p;  p += 2097152 * 2;
    short* qkvb  = (short*)p;  p += 6291456 * 2;
    short* vTb   = (short*)p;  p += 2097152 * 2;
    // aliases of dead buffers:
    float* x2f     = x1f;   // x1f dead after proj epilogue
    short* x2b     = x1b;   // x1b dead after qkv GEMM
    short* attnout = xpad;  // xpad dead after conv GEMM
    short* hb      = qkvb;  // qkvb dead after attention

    cast_all<<<19464, 256, 0, stream>>>(conv_w, qkv_w, proj_w, ffn_w1, ffn_w2, x,
                                        cwT, qkvT, projT, f1T, f2T, xpad);
    gemm_mfma<M_CONV><<<dim3(8, 32), 256, 0, stream>>>(
        xpad, cwT, conv_b, x, yb, nullptr, 1536);
    ln2_kernel<<<4096, 256, 0, stream>>>(yb, g1, b1, x1f, x1b);
    gemm_mfma<M_QKV><<<dim3(24, 32), 256, 0, stream>>>(
        x1b, qkvT, qkv_b, nullptr, qkvb, vTb, 512);
    attn_mfma<<<512, 256, 0, stream>>>(qkvb, vTb, attnout);
    gemm_mfma<M_PROJ><<<dim3(8, 32), 256, 0, stream>>>(
        attnout, projT, proj_b, x1f, yb, nullptr, 512);
    ln2_kernel<<<4096, 256, 0, stream>>>(yb, g2, b2, x2f, x2b);
    gemm_mfma<M_FFN1><<<dim3(16, 32), 256, 0, stream>>>(
        x2b, f1T, ffn_b1, nullptr, hb, nullptr, 512);
    gemm_mfma<M_FFN2><<<dim3(8, 32), 256, 0, stream>>>(
        hb, f2T, ffn_b2, x2f, yb, nullptr, 1024);
    ln2_kernel<<<4096, 256, 0, stream>>>(yb, g3, b3, out, nullptr);
}

// Round 4
// 180.831 us; speedup vs baseline: 1.6052x; 1.6052x over previous
//
#include <hip/hip_runtime.h>
#include <hip/hip_bf16.h>

#define TT 2048

typedef __attribute__((ext_vector_type(4))) float f32x4;
typedef __attribute__((ext_vector_type(8))) __bf16 bf16x8;
typedef __attribute__((ext_vector_type(4))) short short4v;

enum { M_CONV = 0, M_QKV = 1, M_PROJ = 2, M_FFN1 = 3, M_FFN2 = 4 };

__device__ __forceinline__ void gload16(const void* g, void* l) {
    __builtin_amdgcn_global_load_lds(
        (__attribute__((address_space(1))) void*)g,
        (__attribute__((address_space(3))) void*)l, 16, 0, 0);
}

__device__ __forceinline__ short f2bf(float f) {
    unsigned u = __float_as_uint(f);
    u = (u + 0x7fffu + ((u >> 16) & 1u)) >> 16;
    return (short)u;
}

// ---------------------------------------------------------------------------
// One fused cast kernel: all weight transposes + padded x cast.
// ---------------------------------------------------------------------------
__global__ void cast_all(const float* __restrict__ conv_w, const float* __restrict__ qkv_w,
                         const float* __restrict__ proj_w, const float* __restrict__ ffn_w1,
                         const float* __restrict__ ffn_w2, const float* __restrict__ x,
                         short* __restrict__ cwT, short* __restrict__ qkvT,
                         short* __restrict__ projT, short* __restrict__ f1T,
                         short* __restrict__ f2T, short* __restrict__ xpad) {
    int idx = blockIdx.x * 256 + threadIdx.x;
    if (idx < 786432) {                       // conv_w OIH -> [o][tap*512+i]
        int tap = idx >> 18, i = (idx >> 9) & 511, o = idx & 511;
        cwT[(size_t)o * 1536 + tap * 512 + i] = f2bf(conv_w[((size_t)o * 512 + i) * 3 + tap]);
        return;
    }
    idx -= 786432;
    if (idx < 786432) {                       // qkv_w [512][1536] -> [n][k]
        int n = idx >> 9, k = idx & 511;
        qkvT[idx] = f2bf(qkv_w[(size_t)k * 1536 + n]);
        return;
    }
    idx -= 786432;
    if (idx < 262144) {                       // proj_w [512][512] -> [n][k]
        int n = idx >> 9, k = idx & 511;
        projT[idx] = f2bf(proj_w[(size_t)k * 512 + n]);
        return;
    }
    idx -= 262144;
    if (idx < 524288) {                       // ffn_w1 [512][1024] -> [n][k]
        int n = idx >> 9, k = idx & 511;
        f1T[idx] = f2bf(ffn_w1[(size_t)k * 1024 + n]);
        return;
    }
    idx -= 524288;
    if (idx < 524288) {                       // ffn_w2 [1024][512] -> [n][k]
        int n = idx >> 10, k = idx & 1023;
        f2T[idx] = f2bf(ffn_w2[(size_t)k * 512 + n]);
        return;
    }
    idx -= 524288;
    if (idx < 2099200) {                      // x -> xpad [2][2050][512] bf16
        int i = idx & 511, rp = idx >> 9;
        int bb = rp / 2050, rr = rp - bb * 2050;
        int t = rr - 2;
        float v = (t >= 0) ? x[((size_t)(bb << 11) + t) * 512 + i] : 0.f;
        xpad[((size_t)bb * 2050 + rr) * 512 + i] = f2bf(v);
    }
}

// ---------------------------------------------------------------------------
// Row LayerNorm over C=512: f32 in -> f32 out + optional bf16 out
// ---------------------------------------------------------------------------
__global__ __launch_bounds__(256) void ln2_kernel(const float* __restrict__ in,
                                                  const float* __restrict__ g,
                                                  const float* __restrict__ b,
                                                  float* __restrict__ outf,
                                                  short* __restrict__ outb) {
    int row = blockIdx.x;
    int tid = threadIdx.x;
    const float* p = in + (size_t)row * 512;
    float2 v = *(const float2*)(p + tid * 2);
    float s = v.x + v.y;
    float ss = v.x * v.x + v.y * v.y;
    #pragma unroll
    for (int off = 1; off < 64; off <<= 1) {
        s  += __shfl_xor(s, off);
        ss += __shfl_xor(ss, off);
    }
    __shared__ float sm[4], sm2[4];
    int w = tid >> 6;
    if ((tid & 63) == 0) { sm[w] = s; sm2[w] = ss; }
    __syncthreads();
    s  = sm[0] + sm[1] + sm[2] + sm[3];
    ss = sm2[0] + sm2[1] + sm2[2] + sm2[3];
    float mean = s * (1.f / 512);
    float var  = ss * (1.f / 512) - mean * mean;
    float rstd = rsqrtf(var + 1e-5f);
    float2 gg = *(const float2*)(g + tid * 2);
    float2 bb = *(const float2*)(b + tid * 2);
    float ox = (v.x - mean) * rstd * gg.x + bb.x;
    float oy = (v.y - mean) * rstd * gg.y + bb.y;
    *(float2*)(outf + (size_t)row * 512 + tid * 2) = make_float2(ox, oy);
    if (outb) {
        unsigned pk = ((unsigned)(unsigned short)f2bf(oy) << 16) |
                      (unsigned)(unsigned short)f2bf(ox);
        *(unsigned*)&outb[(size_t)row * 512 + tid * 2] = pk;
    }
}

// ---------------------------------------------------------------------------
// bf16 MFMA GEMM (round-2 proven structure): BM=128, BK=32, gload_lds
// staging, single LDS buffer, 4 waves (2x2), wave tile 64 x BN/2.
// ---------------------------------------------------------------------------
template<int MODE, int BN>
__global__ __launch_bounds__(256) void gemm_mfma(
    const short* __restrict__ A, const short* __restrict__ Bw,
    const float* __restrict__ bias, const float* __restrict__ res,
    void* __restrict__ Cout, short* __restrict__ vTb, int K) {
    constexpr int NF = BN / 32;
    __shared__ short As[128 * 32];
    __shared__ short Bs[BN * 32];
    const int tid = threadIdx.x;
    const int w = tid >> 6, l = tid & 63;
    const int wm = w >> 1, wn = w & 1;
    const int lr = l & 15, lc = l >> 4;
    const int m0 = blockIdx.y * 128, n0 = blockIdx.x * BN;
    f32x4 acc[4][NF];
    #pragma unroll
    for (int mf = 0; mf < 4; mf++)
        #pragma unroll
        for (int nf = 0; nf < NF; nf++) acc[mf][nf] = (f32x4){0.f, 0.f, 0.f, 0.f};

    for (int k0 = 0; k0 < K; k0 += 32) {
        #pragma unroll
        for (int i = 0; i < 2; i++) {
            int u = i * 256 + tid;
            int r = u >> 2, c = u & 3;
            const short* gp;
            if constexpr (MODE == M_CONV) {
                int row = m0 + r;
                int bb = row >> 11, t5 = row & 2047;
                int tap = k0 >> 9, kk = k0 & 511;
                gp = A + ((size_t)(bb * 2050 + t5 + tap) * 512 + kk + c * 8);
            } else {
                gp = A + ((size_t)(m0 + r) * K + k0 + c * 8);
            }
            gload16(gp, (char*)As + u * 16);
        }
        #pragma unroll
        for (int i = 0; i < BN / 64; i++) {
            int u = i * 256 + tid;
            int r = u >> 2, c = u & 3;
            gload16(Bw + ((size_t)(n0 + r) * K + k0 + c * 8), (char*)Bs + u * 16);
        }
        __syncthreads();
        bf16x8 af[4];
        #pragma unroll
        for (int mf = 0; mf < 4; mf++)
            af[mf] = *(const bf16x8*)&As[(wm * 64 + mf * 16 + lr) * 32 + lc * 8];
        __builtin_amdgcn_s_setprio(1);
        #pragma unroll
        for (int nf = 0; nf < NF; nf++) {
            bf16x8 bfr = *(const bf16x8*)&Bs[(wn * (BN / 2) + nf * 16 + lr) * 32 + lc * 8];
            #pragma unroll
            for (int mf = 0; mf < 4; mf++)
                acc[mf][nf] = __builtin_amdgcn_mfma_f32_16x16x32_bf16(
                    af[mf], bfr, acc[mf][nf], 0, 0, 0);
        }
        __builtin_amdgcn_s_setprio(0);
        __syncthreads();
    }
    // epilogue
    #pragma unroll
    for (int mf = 0; mf < 4; mf++) {
        int row0 = m0 + wm * 64 + mf * 16 + lc * 4;
        #pragma unroll
        for (int nf = 0; nf < NF; nf++) {
            int col = n0 + wn * (BN / 2) + nf * 16 + lr;
            float bv = bias[col];
            if constexpr (MODE == M_CONV || MODE == M_PROJ || MODE == M_FFN2) {
                float* Cf = (float*)Cout;
                #pragma unroll
                for (int rg = 0; rg < 4; rg++) {
                    size_t off = (size_t)(row0 + rg) * 512 + col;
                    Cf[off] = acc[mf][nf][rg] + bv + res[off];
                }
            } else if constexpr (MODE == M_FFN1) {
                short* Cb = (short*)Cout;
                #pragma unroll
                for (int rg = 0; rg < 4; rg++)
                    Cb[(size_t)(row0 + rg) * 1024 + col] =
                        f2bf(fmaxf(acc[mf][nf][rg] + bv, 0.f));
            } else {  // M_QKV
                short* Cb = (short*)Cout;
                float v[4];
                #pragma unroll
                for (int rg = 0; rg < 4; rg++) {
                    v[rg] = acc[mf][nf][rg] + bv;
                    Cb[(size_t)(row0 + rg) * 1536 + col] = f2bf(v[rg]);
                }
                if (col >= 1024) {  // V transposed: vT[bh][d][t]
                    int vc = col - 1024, hh = vc >> 6, dd = vc & 63;
                    int bb = row0 >> 11, t5 = row0 & 2047;
                    short4v pk = {f2bf(v[0]), f2bf(v[1]), f2bf(v[2]), f2bf(v[3])};
                    *(short4v*)&vTb[((size_t)((bb << 3) + hh) * 64 + dd) * 2048 + t5] = pk;
                }
            }
        }
    }
}

// ---------------------------------------------------------------------------
// bf16 MFMA flash attention, 512 blocks x 512 threads (8 waves).
// Split-KV: waves 0-3 take even KV tiles, waves 4-7 odd tiles; per-wave
// online-softmax state; LSE merge at the end via LDS. gload_lds staging of
// 2 K + 2 V tiles per superstep; swizzled source + swizzled read.
// Block decode: bh = L&15 (XCD L2 clustering), qt = 31-(L>>4) (LPT order).
// ---------------------------------------------------------------------------
__global__ __launch_bounds__(512) void attn_mfma(const short* __restrict__ qkvb,
                                                 const short* __restrict__ vTb,
                                                 short* __restrict__ aout) {
    __shared__ short Qs[64 * 64];
    __shared__ short Ks[2][64 * 64];
    __shared__ short Vs[2][64 * 64];
    __shared__ short Ps[8 * 16 * 72];
    __shared__ float Osm[4][16][68];
    __shared__ float Mm[4][16], Lm[4][16];
    const int tid = threadIdx.x;
    const int w = tid >> 6, l = tid & 63;
    const int half = w >> 2, wq = w & 3;
    const int lr = l & 15, lc = l >> 4;
    const int L = blockIdx.x;
    const int bh = L & 15;
    const int qt = 31 - (L >> 4);
    const int b = bh >> 3, h = bh & 7;
    const int qr = wq * 16, q0 = qt * 64;
    const int pbase = w * 16 * 72;

    // stage Q (one gload per thread: 64x64 shorts = 8192B = 512x16B)
    {
        int u = tid, r = u >> 3, c = (u & 7) ^ (r & 7);
        gload16(qkvb + ((size_t)(b * 2048 + q0 + r) * 1536 + h * 64 + c * 8),
                (char*)Qs + u * 16);
    }

    f32x4 o[4];
    float mst[4], lst[4];
    #pragma unroll
    for (int nf = 0; nf < 4; nf++) o[nf] = (f32x4){0.f, 0.f, 0.f, 0.f};
    #pragma unroll
    for (int rg = 0; rg < 4; rg++) { mst[rg] = -1e30f; lst[rg] = 0.f; }

    const int NS = (qt + 2) >> 1;   // supersteps: each covers kv tiles 2ss, 2ss+1
    for (int ss = 0; ss < NS; ss++) {
        const int kt0 = 2 * ss, kt1 = 2 * ss + 1;
        // ---- stage K/V for both halves ----
        {
            int u = tid, r = u >> 3, c = (u & 7) ^ (r & 7);
            gload16(qkvb + ((size_t)(b * 2048 + kt0 * 64 + r) * 1536 + 512 + h * 64 + c * 8),
                    (char*)Ks[0] + u * 16);
            gload16(vTb + ((size_t)(bh * 64 + r) * 2048 + kt0 * 64 + c * 8),
                    (char*)Vs[0] + u * 16);
            if (kt1 <= qt) {
                gload16(qkvb + ((size_t)(b * 2048 + kt1 * 64 + r) * 1536 + 512 + h * 64 + c * 8),
                        (char*)Ks[1] + u * 16);
                gload16(vTb + ((size_t)(bh * 64 + r) * 2048 + kt1 * 64 + c * 8),
                        (char*)Vs[1] + u * 16);
            }
        }
        __syncthreads();
        const int mykt = 2 * ss + half;
        if (mykt <= qt) {
            // ---- S = Q @ K^T ----
            f32x4 s[4];
            #pragma unroll
            for (int nf = 0; nf < 4; nf++) s[nf] = (f32x4){0.f, 0.f, 0.f, 0.f};
            bf16x8 aq[2];
            #pragma unroll
            for (int ks = 0; ks < 2; ks++) {
                int rr = qr + lr;
                int cc = (lc + 4 * ks) ^ (rr & 7);
                aq[ks] = *(const bf16x8*)&Qs[rr * 64 + cc * 8];
            }
            __builtin_amdgcn_s_setprio(1);
            #pragma unroll
            for (int nf = 0; nf < 4; nf++) {
                #pragma unroll
                for (int ks = 0; ks < 2; ks++) {
                    int rr = nf * 16 + lr;
                    int cc = (lc + 4 * ks) ^ (rr & 7);
                    bf16x8 bk = *(const bf16x8*)&Ks[half][rr * 64 + cc * 8];
                    s[nf] = __builtin_amdgcn_mfma_f32_16x16x32_bf16(aq[ks], bk, s[nf], 0, 0, 0);
                }
            }
            __builtin_amdgcn_s_setprio(0);
            // ---- online softmax with defer-max ----
            const bool diag = (mykt == qt);
            #pragma unroll
            for (int nf = 0; nf < 4; nf++) {
                #pragma unroll
                for (int rg = 0; rg < 4; rg++) {
                    float v = s[nf][rg] * 0.125f;
                    if (diag && (nf * 16 + lr > qr + lc * 4 + rg)) v = -1e30f;
                    s[nf][rg] = v;
                }
            }
            float rm[4];
            int ok = 1;
            #pragma unroll
            for (int rg = 0; rg < 4; rg++) {
                float m_ = fmaxf(fmaxf(s[0][rg], s[1][rg]), fmaxf(s[2][rg], s[3][rg]));
                m_ = fmaxf(m_, __shfl_xor(m_, 1));
                m_ = fmaxf(m_, __shfl_xor(m_, 2));
                m_ = fmaxf(m_, __shfl_xor(m_, 4));
                m_ = fmaxf(m_, __shfl_xor(m_, 8));
                rm[rg] = m_;
                ok &= (m_ <= mst[rg] + 8.f);
            }
            if (!__all(ok)) {
                #pragma unroll
                for (int rg = 0; rg < 4; rg++) {
                    float mn = fmaxf(mst[rg], rm[rg]);
                    float alpha = __expf(mst[rg] - mn);
                    mst[rg] = mn;
                    lst[rg] *= alpha;
                    #pragma unroll
                    for (int nf = 0; nf < 4; nf++) o[nf][rg] *= alpha;
                }
            }
            #pragma unroll
            for (int rg = 0; rg < 4; rg++) {
                float p0 = __expf(s[0][rg] - mst[rg]);
                float p1 = __expf(s[1][rg] - mst[rg]);
                float p2 = __expf(s[2][rg] - mst[rg]);
                float p3 = __expf(s[3][rg] - mst[rg]);
                int prow = pbase + (lc * 4 + rg) * 72;
                Ps[prow      + lr] = f2bf(p0);
                Ps[prow + 16 + lr] = f2bf(p1);
                Ps[prow + 32 + lr] = f2bf(p2);
                Ps[prow + 48 + lr] = f2bf(p3);
                float rs = p0 + p1 + p2 + p3;
                rs += __shfl_xor(rs, 1);
                rs += __shfl_xor(rs, 2);
                rs += __shfl_xor(rs, 4);
                rs += __shfl_xor(rs, 8);
                lst[rg] += rs;
            }
            // ---- O += P @ V ----
            bf16x8 pa[2];
            #pragma unroll
            for (int ks = 0; ks < 2; ks++)
                pa[ks] = *(const bf16x8*)&Ps[pbase + lr * 72 + ks * 32 + lc * 8];
            __builtin_amdgcn_s_setprio(1);
            #pragma unroll
            for (int nf = 0; nf < 4; nf++) {
                #pragma unroll
                for (int ks = 0; ks < 2; ks++) {
                    int rr = nf * 16 + lr;
                    int cc = (lc + 4 * ks) ^ (rr & 7);
                    bf16x8 bv = *(const bf16x8*)&Vs[half][rr * 64 + cc * 8];
                    o[nf] = __builtin_amdgcn_mfma_f32_16x16x32_bf16(pa[ks], bv, o[nf], 0, 0, 0);
                }
            }
            __builtin_amdgcn_s_setprio(0);
        }
        __syncthreads();
    }

    // ---- merge halves (LSE merge) ----
    if (half == 1) {
        #pragma unroll
        for (int rg = 0; rg < 4; rg++) {
            int row = lc * 4 + rg;
            if (lr == 0) { Mm[wq][row] = mst[rg]; Lm[wq][row] = lst[rg]; }
            #pragma unroll
            for (int nf = 0; nf < 4; nf++)
                Osm[wq][row][nf * 16 + lr] = o[nf][rg];
        }
    }
    __syncthreads();
    if (half == 0) {
        #pragma unroll
        for (int rg = 0; rg < 4; rg++) {
            int row = lc * 4 + rg;
            float m2 = Mm[wq][row], l2 = Lm[wq][row];
            float mn = fmaxf(mst[rg], m2);
            float a1 = __expf(mst[rg] - mn);
            float a2 = __expf(m2 - mn);
            float lm = lst[rg] * a1 + l2 * a2;
            float inv = 1.f / lm;
            #pragma unroll
            for (int nf = 0; nf < 4; nf++) {
                float ov = (o[nf][rg] * a1 + Osm[wq][row][nf * 16 + lr] * a2) * inv;
                aout[(size_t)(b * 2048 + q0 + qr + row) * 512 + h * 64 + nf * 16 + lr] =
                    f2bf(ov);
            }
        }
    }
}

// ---------------------------------------------------------------------------
extern "C" void kernel_launch(void* const* d_in, const int* in_sizes, int n_in,
                              void* d_out, int out_size, void* d_ws, size_t ws_size,
                              hipStream_t stream) {
    const float* x      = (const float*)d_in[0];
    const float* conv_w = (const float*)d_in[1];
    const float* conv_b = (const float*)d_in[2];
    const float* g1     = (const float*)d_in[3];
    const float* b1     = (const float*)d_in[4];
    const float* qkv_w  = (const float*)d_in[5];
    const float* qkv_b  = (const float*)d_in[6];
    const float* proj_w = (const float*)d_in[7];
    const float* proj_b = (const float*)d_in[8];
    const float* g2     = (const float*)d_in[9];
    const float* b2     = (const float*)d_in[10];
    const float* ffn_w1 = (const float*)d_in[11];
    const float* ffn_b1 = (const float*)d_in[12];
    const float* ffn_w2 = (const float*)d_in[13];
    const float* ffn_b2 = (const float*)d_in[14];
    const float* g3     = (const float*)d_in[15];
    const float* b3     = (const float*)d_in[16];
    float* out = (float*)d_out;

    char* p = (char*)d_ws;
    short* cwT   = (short*)p;  p += 786432 * 2;
    short* qkvT  = (short*)p;  p += 786432 * 2;
    short* projT = (short*)p;  p += 262144 * 2;
    short* f1T   = (short*)p;  p += 524288 * 2;
    short* f2T   = (short*)p;  p += 524288 * 2;
    short* xpad  = (short*)p;  p += 2099200 * 2;
    float* yb    = (float*)p;  p += 2097152 * 4;
    float* x1f   = (float*)p;  p += 2097152 * 4;
    short* x1b   = (short*)p;  p += 2097152 * 2;
    short* qkvb  = (short*)p;  p += 6291456 * 2;
    short* vTb   = (short*)p;  p += 2097152 * 2;
    // aliases of dead buffers:
    float* x2f     = x1f;   // x1f dead after proj epilogue
    short* x2b     = x1b;   // x1b dead after qkv GEMM
    short* attnout = xpad;  // xpad dead after conv GEMM
    short* hb      = qkvb;  // qkvb dead after attention

    cast_all<<<19464, 256, 0, stream>>>(conv_w, qkv_w, proj_w, ffn_w1, ffn_w2, x,
                                        cwT, qkvT, projT, f1T, f2T, xpad);
    gemm_mfma<M_CONV, 64><<<dim3(8, 32), 256, 0, stream>>>(
        xpad, cwT, conv_b, x, yb, nullptr, 1536);
    ln2_kernel<<<4096, 256, 0, stream>>>(yb, g1, b1, x1f, x1b);
    gemm_mfma<M_QKV, 128><<<dim3(12, 32), 256, 0, stream>>>(
        x1b, qkvT, qkv_b, nullptr, qkvb, vTb, 512);
    attn_mfma<<<512, 512, 0, stream>>>(qkvb, vTb, attnout);
    gemm_mfma<M_PROJ, 64><<<dim3(8, 32), 256, 0, stream>>>(
        attnout, projT, proj_b, x1f, yb, nullptr, 512);
    ln2_kernel<<<4096, 256, 0, stream>>>(yb, g2, b2, x2f, x2b);
    gemm_mfma<M_FFN1, 128><<<dim3(8, 32), 256, 0, stream>>>(
        x2b, f1T, ffn_b1, nullptr, hb, nullptr, 512);
    gemm_mfma<M_FFN2, 64><<<dim3(8, 32), 256, 0, stream>>>(
        hb, f2T, ffn_b2, x2f, yb, nullptr, 1024);
    ln2_kernel<<<4096, 256, 0, stream>>>(yb, g3, b3, out, nullptr);
}

// Round 5
// 149.583 us; speedup vs baseline: 1.9406x; 1.2089x over previous
//
#include <hip/hip_runtime.h>
#include <hip/hip_bf16.h>

#define TT 2048

typedef __attribute__((ext_vector_type(4))) float f32x4;
typedef __attribute__((ext_vector_type(8))) __bf16 bf16x8;
typedef __attribute__((ext_vector_type(4))) short short4v;

enum { M_CONV = 0, M_QKV = 1, M_PROJ = 2, M_FFN1 = 3, M_FFN2 = 4 };

__device__ __forceinline__ void gload16(const void* g, void* l) {
    __builtin_amdgcn_global_load_lds(
        (__attribute__((address_space(1))) void*)g,
        (__attribute__((address_space(3))) void*)l, 16, 0, 0);
}

__device__ __forceinline__ short f2bf(float f) {
    unsigned u = __float_as_uint(f);
    u = (u + 0x7fffu + ((u >> 16) & 1u)) >> 16;
    return (short)u;
}

// ---------------------------------------------------------------------------
// One fused cast kernel: all weight transposes + padded x cast.
// ---------------------------------------------------------------------------
__global__ void cast_all(const float* __restrict__ conv_w, const float* __restrict__ qkv_w,
                         const float* __restrict__ proj_w, const float* __restrict__ ffn_w1,
                         const float* __restrict__ ffn_w2, const float* __restrict__ x,
                         short* __restrict__ cwT, short* __restrict__ qkvT,
                         short* __restrict__ projT, short* __restrict__ f1T,
                         short* __restrict__ f2T, short* __restrict__ xpad) {
    int idx = blockIdx.x * 256 + threadIdx.x;
    if (idx < 786432) {                       // conv_w OIH -> [o][tap*512+i]
        int tap = idx >> 18, i = (idx >> 9) & 511, o = idx & 511;
        cwT[(size_t)o * 1536 + tap * 512 + i] = f2bf(conv_w[((size_t)o * 512 + i) * 3 + tap]);
        return;
    }
    idx -= 786432;
    if (idx < 786432) {                       // qkv_w [512][1536] -> [n][k]
        int n = idx >> 9, k = idx & 511;
        qkvT[idx] = f2bf(qkv_w[(size_t)k * 1536 + n]);
        return;
    }
    idx -= 786432;
    if (idx < 262144) {                       // proj_w [512][512] -> [n][k]
        int n = idx >> 9, k = idx & 511;
        projT[idx] = f2bf(proj_w[(size_t)k * 512 + n]);
        return;
    }
    idx -= 262144;
    if (idx < 524288) {                       // ffn_w1 [512][1024] -> [n][k]
        int n = idx >> 9, k = idx & 511;
        f1T[idx] = f2bf(ffn_w1[(size_t)k * 1024 + n]);
        return;
    }
    idx -= 524288;
    if (idx < 524288) {                       // ffn_w2 [1024][512] -> [n][k]
        int n = idx >> 10, k = idx & 1023;
        f2T[idx] = f2bf(ffn_w2[(size_t)k * 512 + n]);
        return;
    }
    idx -= 524288;
    if (idx < 2099200) {                      // x -> xpad [2][2050][512] bf16
        int i = idx & 511, rp = idx >> 9;
        int bb = rp / 2050, rr = rp - bb * 2050;
        int t = rr - 2;
        float v = (t >= 0) ? x[((size_t)(bb << 11) + t) * 512 + i] : 0.f;
        xpad[((size_t)bb * 2050 + rr) * 512 + i] = f2bf(v);
    }
}

// ---------------------------------------------------------------------------
// Row LayerNorm over C=512: f32 in -> f32 out + optional bf16 out
// ---------------------------------------------------------------------------
__global__ __launch_bounds__(256) void ln2_kernel(const float* __restrict__ in,
                                                  const float* __restrict__ g,
                                                  const float* __restrict__ b,
                                                  float* __restrict__ outf,
                                                  short* __restrict__ outb) {
    int row = blockIdx.x;
    int tid = threadIdx.x;
    const float* p = in + (size_t)row * 512;
    float2 v = *(const float2*)(p + tid * 2);
    float s = v.x + v.y;
    float ss = v.x * v.x + v.y * v.y;
    #pragma unroll
    for (int off = 1; off < 64; off <<= 1) {
        s  += __shfl_xor(s, off);
        ss += __shfl_xor(ss, off);
    }
    __shared__ float sm[4], sm2[4];
    int w = tid >> 6;
    if ((tid & 63) == 0) { sm[w] = s; sm2[w] = ss; }
    __syncthreads();
    s  = sm[0] + sm[1] + sm[2] + sm[3];
    ss = sm2[0] + sm2[1] + sm2[2] + sm2[3];
    float mean = s * (1.f / 512);
    float var  = ss * (1.f / 512) - mean * mean;
    float rstd = rsqrtf(var + 1e-5f);
    float2 gg = *(const float2*)(g + tid * 2);
    float2 bb = *(const float2*)(b + tid * 2);
    float ox = (v.x - mean) * rstd * gg.x + bb.x;
    float oy = (v.y - mean) * rstd * gg.y + bb.y;
    *(float2*)(outf + (size_t)row * 512 + tid * 2) = make_float2(ox, oy);
    if (outb) {
        unsigned pk = ((unsigned)(unsigned short)f2bf(oy) << 16) |
                      (unsigned)(unsigned short)f2bf(ox);
        *(unsigned*)&outb[(size_t)row * 512 + tid * 2] = pk;
    }
}

// ---------------------------------------------------------------------------
// A-operand global address (handles conv's padded/3-tap layout)
// ---------------------------------------------------------------------------
template<int MODE>
__device__ __forceinline__ const short* a_ptr(const short* A, int m0, int r, int kk, int K) {
    if constexpr (MODE == M_CONV) {
        int row = m0 + r;
        int bb = row >> 11, t5 = row & 2047;
        int tap = kk >> 9, k2 = kk & 511;
        return A + ((size_t)(bb * 2050 + t5 + tap) * 512 + k2);
    } else {
        return A + ((size_t)(m0 + r) * K + kk);
    }
}

// ---------------------------------------------------------------------------
// bf16 MFMA GEMM: BM=64, BN=64, BK=64, gload_lds staging, single LDS buffer,
// 4 waves (2x2), wave tile 32x32. Small tiles -> 512-1536 blocks (2-6/CU)
// for latency hiding. LDS tiles [64][64] chunk-swizzled (c ^= r&7) on both
// staging-source and read side. grid: (x = M-blocks, y = N-blocks) so
// consecutive blocks share the small B panel in L2.
// ---------------------------------------------------------------------------
template<int MODE>
__global__ __launch_bounds__(256) void gemm_mfma(
    const short* __restrict__ A, const short* __restrict__ Bw,
    const float* __restrict__ bias, const float* __restrict__ res,
    void* __restrict__ Cout, short* __restrict__ vTb, int K) {
    __shared__ short As[64 * 64];
    __shared__ short Bs[64 * 64];
    const int tid = threadIdx.x;
    const int w = tid >> 6, l = tid & 63;
    const int wm = w >> 1, wn = w & 1;
    const int lr = l & 15, lc = l >> 4;
    const int m0 = blockIdx.x * 64, n0 = blockIdx.y * 64;
    f32x4 acc[2][2];
    #pragma unroll
    for (int mf = 0; mf < 2; mf++)
        #pragma unroll
        for (int nf = 0; nf < 2; nf++) acc[mf][nf] = (f32x4){0.f, 0.f, 0.f, 0.f};

    for (int k0 = 0; k0 < K; k0 += 64) {
        #pragma unroll
        for (int i = 0; i < 2; i++) {
            int u = i * 256 + tid;
            int r = u >> 3, c = (u & 7) ^ (r & 7);
            gload16(a_ptr<MODE>(A, m0, r, k0 + c * 8, K), (char*)As + u * 16);
            gload16(Bw + ((size_t)(n0 + r) * K + k0 + c * 8), (char*)Bs + u * 16);
        }
        __syncthreads();
        bf16x8 af[2][2], bfv[2][2];
        #pragma unroll
        for (int mf = 0; mf < 2; mf++)
            #pragma unroll
            for (int ks = 0; ks < 2; ks++) {
                int rr = wm * 32 + mf * 16 + lr;
                int cc = (ks * 4 + lc) ^ (rr & 7);
                af[mf][ks] = *(const bf16x8*)&As[rr * 64 + cc * 8];
            }
        #pragma unroll
        for (int nf = 0; nf < 2; nf++)
            #pragma unroll
            for (int ks = 0; ks < 2; ks++) {
                int rr = wn * 32 + nf * 16 + lr;
                int cc = (ks * 4 + lc) ^ (rr & 7);
                bfv[nf][ks] = *(const bf16x8*)&Bs[rr * 64 + cc * 8];
            }
        __builtin_amdgcn_s_setprio(1);
        #pragma unroll
        for (int nf = 0; nf < 2; nf++)
            #pragma unroll
            for (int ks = 0; ks < 2; ks++)
                #pragma unroll
                for (int mf = 0; mf < 2; mf++)
                    acc[mf][nf] = __builtin_amdgcn_mfma_f32_16x16x32_bf16(
                        af[mf][ks], bfv[nf][ks], acc[mf][nf], 0, 0, 0);
        __builtin_amdgcn_s_setprio(0);
        __syncthreads();
    }
    // epilogue
    #pragma unroll
    for (int mf = 0; mf < 2; mf++) {
        int row0 = m0 + wm * 32 + mf * 16 + lc * 4;
        #pragma unroll
        for (int nf = 0; nf < 2; nf++) {
            int col = n0 + wn * 32 + nf * 16 + lr;
            float bv = bias[col];
            if constexpr (MODE == M_CONV || MODE == M_PROJ || MODE == M_FFN2) {
                float* Cf = (float*)Cout;
                #pragma unroll
                for (int rg = 0; rg < 4; rg++) {
                    size_t off = (size_t)(row0 + rg) * 512 + col;
                    Cf[off] = acc[mf][nf][rg] + bv + res[off];
                }
            } else if constexpr (MODE == M_FFN1) {
                short* Cb = (short*)Cout;
                #pragma unroll
                for (int rg = 0; rg < 4; rg++)
                    Cb[(size_t)(row0 + rg) * 1024 + col] =
                        f2bf(fmaxf(acc[mf][nf][rg] + bv, 0.f));
            } else {  // M_QKV
                short* Cb = (short*)Cout;
                float v[4];
                #pragma unroll
                for (int rg = 0; rg < 4; rg++) {
                    v[rg] = acc[mf][nf][rg] + bv;
                    Cb[(size_t)(row0 + rg) * 1536 + col] = f2bf(v[rg]);
                }
                if (col >= 1024) {  // V transposed: vT[bh][d][t]
                    int vc = col - 1024, hh = vc >> 6, dd = vc & 63;
                    int bb = row0 >> 11, t5 = row0 & 2047;
                    short4v pk = {f2bf(v[0]), f2bf(v[1]), f2bf(v[2]), f2bf(v[3])};
                    *(short4v*)&vTb[((size_t)((bb << 3) + hh) * 64 + dd) * 2048 + t5] = pk;
                }
            }
        }
    }
}

// ---------------------------------------------------------------------------
// bf16 MFMA flash attention, 512 blocks x 512 threads (8 waves).
// Split-KV: waves 0-3 take even KV tiles, waves 4-7 odd tiles; per-wave
// online-softmax state; LSE merge at the end via LDS. gload_lds staging of
// 2 K + 2 V tiles per superstep; swizzled source + swizzled read.
// Block decode: bh = L&15 (XCD L2 clustering), qt = 31-(L>>4) (LPT order).
// ---------------------------------------------------------------------------
__global__ __launch_bounds__(512) void attn_mfma(const short* __restrict__ qkvb,
                                                 const short* __restrict__ vTb,
                                                 short* __restrict__ aout) {
    __shared__ short Qs[64 * 64];
    __shared__ short Ks[2][64 * 64];
    __shared__ short Vs[2][64 * 64];
    __shared__ short Ps[8 * 16 * 72];
    __shared__ float Osm[4][16][68];
    __shared__ float Mm[4][16], Lm[4][16];
    const int tid = threadIdx.x;
    const int w = tid >> 6, l = tid & 63;
    const int half = w >> 2, wq = w & 3;
    const int lr = l & 15, lc = l >> 4;
    const int L = blockIdx.x;
    const int bh = L & 15;
    const int qt = 31 - (L >> 4);
    const int b = bh >> 3, h = bh & 7;
    const int qr = wq * 16, q0 = qt * 64;
    const int pbase = w * 16 * 72;

    // stage Q (one gload per thread: 64x64 shorts = 8192B = 512x16B)
    {
        int u = tid, r = u >> 3, c = (u & 7) ^ (r & 7);
        gload16(qkvb + ((size_t)(b * 2048 + q0 + r) * 1536 + h * 64 + c * 8),
                (char*)Qs + u * 16);
    }

    f32x4 o[4];
    float mst[4], lst[4];
    #pragma unroll
    for (int nf = 0; nf < 4; nf++) o[nf] = (f32x4){0.f, 0.f, 0.f, 0.f};
    #pragma unroll
    for (int rg = 0; rg < 4; rg++) { mst[rg] = -1e30f; lst[rg] = 0.f; }

    const int NS = (qt + 2) >> 1;   // supersteps: each covers kv tiles 2ss, 2ss+1
    for (int ss = 0; ss < NS; ss++) {
        const int kt0 = 2 * ss, kt1 = 2 * ss + 1;
        // ---- stage K/V for both halves ----
        {
            int u = tid, r = u >> 3, c = (u & 7) ^ (r & 7);
            gload16(qkvb + ((size_t)(b * 2048 + kt0 * 64 + r) * 1536 + 512 + h * 64 + c * 8),
                    (char*)Ks[0] + u * 16);
            gload16(vTb + ((size_t)(bh * 64 + r) * 2048 + kt0 * 64 + c * 8),
                    (char*)Vs[0] + u * 16);
            if (kt1 <= qt) {
                gload16(qkvb + ((size_t)(b * 2048 + kt1 * 64 + r) * 1536 + 512 + h * 64 + c * 8),
                        (char*)Ks[1] + u * 16);
                gload16(vTb + ((size_t)(bh * 64 + r) * 2048 + kt1 * 64 + c * 8),
                        (char*)Vs[1] + u * 16);
            }
        }
        __syncthreads();
        const int mykt = 2 * ss + half;
        if (mykt <= qt) {
            // ---- S = Q @ K^T ----
            f32x4 s[4];
            #pragma unroll
            for (int nf = 0; nf < 4; nf++) s[nf] = (f32x4){0.f, 0.f, 0.f, 0.f};
            bf16x8 aq[2];
            #pragma unroll
            for (int ks = 0; ks < 2; ks++) {
                int rr = qr + lr;
                int cc = (lc + 4 * ks) ^ (rr & 7);
                aq[ks] = *(const bf16x8*)&Qs[rr * 64 + cc * 8];
            }
            __builtin_amdgcn_s_setprio(1);
            #pragma unroll
            for (int nf = 0; nf < 4; nf++) {
                #pragma unroll
                for (int ks = 0; ks < 2; ks++) {
                    int rr = nf * 16 + lr;
                    int cc = (lc + 4 * ks) ^ (rr & 7);
                    bf16x8 bk = *(const bf16x8*)&Ks[half][rr * 64 + cc * 8];
                    s[nf] = __builtin_amdgcn_mfma_f32_16x16x32_bf16(aq[ks], bk, s[nf], 0, 0, 0);
                }
            }
            __builtin_amdgcn_s_setprio(0);
            // ---- online softmax with defer-max ----
            const bool diag = (mykt == qt);
            #pragma unroll
            for (int nf = 0; nf < 4; nf++) {
                #pragma unroll
                for (int rg = 0; rg < 4; rg++) {
                    float v = s[nf][rg] * 0.125f;
                    if (diag && (nf * 16 + lr > qr + lc * 4 + rg)) v = -1e30f;
                    s[nf][rg] = v;
                }
            }
            float rm[4];
            int ok = 1;
            #pragma unroll
            for (int rg = 0; rg < 4; rg++) {
                float m_ = fmaxf(fmaxf(s[0][rg], s[1][rg]), fmaxf(s[2][rg], s[3][rg]));
                m_ = fmaxf(m_, __shfl_xor(m_, 1));
                m_ = fmaxf(m_, __shfl_xor(m_, 2));
                m_ = fmaxf(m_, __shfl_xor(m_, 4));
                m_ = fmaxf(m_, __shfl_xor(m_, 8));
                rm[rg] = m_;
                ok &= (m_ <= mst[rg] + 8.f);
            }
            if (!__all(ok)) {
                #pragma unroll
                for (int rg = 0; rg < 4; rg++) {
                    float mn = fmaxf(mst[rg], rm[rg]);
                    float alpha = __expf(mst[rg] - mn);
                    mst[rg] = mn;
                    lst[rg] *= alpha;
                    #pragma unroll
                    for (int nf = 0; nf < 4; nf++) o[nf][rg] *= alpha;
                }
            }
            #pragma unroll
            for (int rg = 0; rg < 4; rg++) {
                float p0 = __expf(s[0][rg] - mst[rg]);
                float p1 = __expf(s[1][rg] - mst[rg]);
                float p2 = __expf(s[2][rg] - mst[rg]);
                float p3 = __expf(s[3][rg] - mst[rg]);
                int prow = pbase + (lc * 4 + rg) * 72;
                Ps[prow      + lr] = f2bf(p0);
                Ps[prow + 16 + lr] = f2bf(p1);
                Ps[prow + 32 + lr] = f2bf(p2);
                Ps[prow + 48 + lr] = f2bf(p3);
                float rs = p0 + p1 + p2 + p3;
                rs += __shfl_xor(rs, 1);
                rs += __shfl_xor(rs, 2);
                rs += __shfl_xor(rs, 4);
                rs += __shfl_xor(rs, 8);
                lst[rg] += rs;
            }
            // ---- O += P @ V ----
            bf16x8 pa[2];
            #pragma unroll
            for (int ks = 0; ks < 2; ks++)
                pa[ks] = *(const bf16x8*)&Ps[pbase + lr * 72 + ks * 32 + lc * 8];
            __builtin_amdgcn_s_setprio(1);
            #pragma unroll
            for (int nf = 0; nf < 4; nf++) {
                #pragma unroll
                for (int ks = 0; ks < 2; ks++) {
                    int rr = nf * 16 + lr;
                    int cc = (lc + 4 * ks) ^ (rr & 7);
                    bf16x8 bv = *(const bf16x8*)&Vs[half][rr * 64 + cc * 8];
                    o[nf] = __builtin_amdgcn_mfma_f32_16x16x32_bf16(pa[ks], bv, o[nf], 0, 0, 0);
                }
            }
            __builtin_amdgcn_s_setprio(0);
        }
        __syncthreads();
    }

    // ---- merge halves (LSE merge) ----
    if (half == 1) {
        #pragma unroll
        for (int rg = 0; rg < 4; rg++) {
            int row = lc * 4 + rg;
            if (lr == 0) { Mm[wq][row] = mst[rg]; Lm[wq][row] = lst[rg]; }
            #pragma unroll
            for (int nf = 0; nf < 4; nf++)
                Osm[wq][row][nf * 16 + lr] = o[nf][rg];
        }
    }
    __syncthreads();
    if (half == 0) {
        #pragma unroll
        for (int rg = 0; rg < 4; rg++) {
            int row = lc * 4 + rg;
            float m2 = Mm[wq][row], l2 = Lm[wq][row];
            float mn = fmaxf(mst[rg], m2);
            float a1 = __expf(mst[rg] - mn);
            float a2 = __expf(m2 - mn);
            float lm = lst[rg] * a1 + l2 * a2;
            float inv = 1.f / lm;
            #pragma unroll
            for (int nf = 0; nf < 4; nf++) {
                float ov = (o[nf][rg] * a1 + Osm[wq][row][nf * 16 + lr] * a2) * inv;
                aout[(size_t)(b * 2048 + q0 + qr + row) * 512 + h * 64 + nf * 16 + lr] =
                    f2bf(ov);
            }
        }
    }
}

// ---------------------------------------------------------------------------
extern "C" void kernel_launch(void* const* d_in, const int* in_sizes, int n_in,
                              void* d_out, int out_size, void* d_ws, size_t ws_size,
                              hipStream_t stream) {
    const float* x      = (const float*)d_in[0];
    const float* conv_w = (const float*)d_in[1];
    const float* conv_b = (const float*)d_in[2];
    const float* g1     = (const float*)d_in[3];
    const float* b1     = (const float*)d_in[4];
    const float* qkv_w  = (const float*)d_in[5];
    const float* qkv_b  = (const float*)d_in[6];
    const float* proj_w = (const float*)d_in[7];
    const float* proj_b = (const float*)d_in[8];
    const float* g2     = (const float*)d_in[9];
    const float* b2     = (const float*)d_in[10];
    const float* ffn_w1 = (const float*)d_in[11];
    const float* ffn_b1 = (const float*)d_in[12];
    const float* ffn_w2 = (const float*)d_in[13];
    const float* ffn_b2 = (const float*)d_in[14];
    const float* g3     = (const float*)d_in[15];
    const float* b3     = (const float*)d_in[16];
    float* out = (float*)d_out;

    char* p = (char*)d_ws;
    short* cwT   = (short*)p;  p += 786432 * 2;
    short* qkvT  = (short*)p;  p += 786432 * 2;
    short* projT = (short*)p;  p += 262144 * 2;
    short* f1T   = (short*)p;  p += 524288 * 2;
    short* f2T   = (short*)p;  p += 524288 * 2;
    short* xpad  = (short*)p;  p += 2099200 * 2;
    float* yb    = (float*)p;  p += 2097152 * 4;
    float* x1f   = (float*)p;  p += 2097152 * 4;
    short* x1b   = (short*)p;  p += 2097152 * 2;
    short* qkvb  = (short*)p;  p += 6291456 * 2;
    short* vTb   = (short*)p;  p += 2097152 * 2;
    // aliases of dead buffers:
    float* x2f     = x1f;   // x1f dead after proj epilogue
    short* x2b     = x1b;   // x1b dead after qkv GEMM
    short* attnout = xpad;  // xpad dead after conv GEMM
    short* hb      = qkvb;  // qkvb dead after attention

    cast_all<<<19464, 256, 0, stream>>>(conv_w, qkv_w, proj_w, ffn_w1, ffn_w2, x,
                                        cwT, qkvT, projT, f1T, f2T, xpad);
    gemm_mfma<M_CONV><<<dim3(64, 8), 256, 0, stream>>>(
        xpad, cwT, conv_b, x, yb, nullptr, 1536);
    ln2_kernel<<<4096, 256, 0, stream>>>(yb, g1, b1, x1f, x1b);
    gemm_mfma<M_QKV><<<dim3(64, 24), 256, 0, stream>>>(
        x1b, qkvT, qkv_b, nullptr, qkvb, vTb, 512);
    attn_mfma<<<512, 512, 0, stream>>>(qkvb, vTb, attnout);
    gemm_mfma<M_PROJ><<<dim3(64, 8), 256, 0, stream>>>(
        attnout, projT, proj_b, x1f, yb, nullptr, 512);
    ln2_kernel<<<4096, 256, 0, stream>>>(yb, g2, b2, x2f, x2b);
    gemm_mfma<M_FFN1><<<dim3(64, 16), 256, 0, stream>>>(
        x2b, f1T, ffn_b1, nullptr, hb, nullptr, 512);
    gemm_mfma<M_FFN2><<<dim3(64, 8), 256, 0, stream>>>(
        hb, f2T, ffn_b2, x2f, yb, nullptr, 1024);
    ln2_kernel<<<4096, 256, 0, stream>>>(yb, g3, b3, out, nullptr);
}